// Round 8
// baseline (215.608 us; speedup 1.0000x reference)
//
#include <hip/hip_runtime.h>

#define NF    50000
#define PADP  50001
#define KN    9
#define KTOT  2304
#define NCHUNK 782
#define NT    72          // 2304/32 K-tiles
#define BM    128
#define NBLK  391         // ceil(50000/128)
#define SLOT  16384       // one B tile: 256 rows x 64B
#define RSZ   49152       // ring-3

// ---- ws layout (bytes) ----
#define WT_OFF   0u          // 256*2304*2 = 1179648
#define FLAG_OFF 1179648u
#define CNT_OFF  1179904u    // 782*4
#define PADX_OFF 1183744u    // 50001*256*2

typedef float f32x4 __attribute__((ext_vector_type(4)));
typedef __bf16 bf16x8 __attribute__((ext_vector_type(8)));

typedef const __attribute__((address_space(1))) unsigned int* gas_t;
typedef __attribute__((address_space(3))) unsigned int* las_t;

static __device__ __forceinline__ void gll16(const void* g, void* l) {
  __builtin_amdgcn_global_load_lds((gas_t)g, (las_t)l, 16, 0, 0);
}

static __device__ __forceinline__ unsigned short f2bf(float f) {
  unsigned int u = __builtin_bit_cast(unsigned int, f);
  u = u + 0x7fffu + ((u >> 16) & 1u);      // RNE
  return (unsigned short)(u >> 16);
}

// ---------- preprocessing ----------

// fused: weight demod+transpose (blocks 0..255) | pad chunk counts + flag (blocks 256..451)
__global__ void k_prep(const float* __restrict__ w, unsigned short* __restrict__ wt,
                       const unsigned char* __restrict__ pad, int* __restrict__ cnt,
                       const unsigned int* __restrict__ raw, int* __restrict__ flag) {
  if (blockIdx.x < 256) {
    int o = blockIdx.x;
    int i = threadIdx.x;
    const float* wr = w + (o * 256 + i) * 9;
    float wv[9];
    float s = 0.f;
#pragma unroll
    for (int k = 0; k < 9; ++k) { wv[k] = wr[k]; s += wv[k] * wv[k]; }
#pragma unroll
    for (int d = 32; d >= 1; d >>= 1) s += __shfl_xor(s, d);
    __shared__ float red[4];
    if ((i & 63) == 0) red[i >> 6] = s;
    __syncthreads();
    float dc = rsqrtf(red[0] + red[1] + red[2] + red[3] + 1e-8f);
#pragma unroll
    for (int k = 0; k < 9; ++k)
      wt[o * KTOT + k * 256 + i] = f2bf(wv[k] * dc);
  } else {
    int cb = blockIdx.x - 256;
    int t = cb * 256 + threadIdx.x;
    bool ip = (t < PADP) ? (pad[t] != 0) : true;
    unsigned long long m = __ballot(ip);
    int c = t >> 6;
    if ((threadIdx.x & 63) == 0 && c < NCHUNK) cnt[c] = __popcll(m);
    if (cb == 0 && threadIdx.x < 64) {
      unsigned int v = raw[threadIdx.x * 2 + 1];
      unsigned long long nz = __ballot(v != 0u);
      if (threadIdx.x == 0) flag[0] = (nz == 0ull) ? 1 : 0;
    }
  }
}

// one block per 64-row chunk: prefix over cnt -> ranks -> bf16 conversion
__global__ __launch_bounds__(256) void k_rankpadx(
    const float* __restrict__ x, const unsigned char* __restrict__ pad,
    const int* __restrict__ cnt, unsigned short* __restrict__ padx) {
  const int c = blockIdx.x;
  const int tid = threadIdx.x, w = tid >> 6, lane = tid & 63;
  int s = 0;
  for (int i = tid; i < c; i += 256) s += cnt[i];
#pragma unroll
  for (int d = 32; d >= 1; d >>= 1) s += __shfl_xor(s, d);
  __shared__ int red[4];
  __shared__ int rnk[64];
  if (lane == 0) red[w] = s;
  __syncthreads();
  const int S = red[0] + red[1] + red[2] + red[3];
  if (w == 0) {
    int p = c * 64 + lane;
    bool ip = (p < PADP) ? (pad[p] != 0) : true;
    unsigned long long m = __ballot(ip);
    int before = __popcll(m & ((1ull << lane) - 1ull));
    rnk[lane] = ip ? -1 : (p - (S + before));
  }
  __syncthreads();
  const int col = lane * 4;
#pragma unroll
  for (int i = 0; i < 16; ++i) {
    int rl = i * 4 + w;
    int pp = c * 64 + rl;
    if (pp >= PADP) continue;
    int rr = rnk[rl];
    ushort4 ov;
    if (rr < 0) { ov.x = 0; ov.y = 0; ov.z = 0; ov.w = 0; }
    else {
      const float4 v = *(const float4*)(x + rr * 256 + col);
      ov.x = f2bf(v.x); ov.y = f2bf(v.y); ov.z = f2bf(v.z); ov.w = f2bf(v.w);
    }
    *(ushort4*)(padx + pp * 256 + col) = ov;
  }
}

// ---------- main gathered GEMM ----------
// BM=128 x BN=256 x BK=32, 512 thr (8 waves 2M x 4N), wave-tile 64x64 (4x4).
// A: DIRECT-TO-REGISTER gather (1 dwordx4/frag: lane l reads 16B of row(l&15)
//    at k-quad l>>4). Per-wave elastic: gather stalls drain at the compiler's
//    pre-MFMA vmcnt, NOT at the barrier.
// B: LDS ring-3 x 16KB, 2 gll16/thread/tile, frag ping-pong prefetch (t+1).
// Per-iter vmem order: [ds_read(t+1) | idx(J0) | gll16 B(t+2)] fence
//   [A(t+1) x4] fence MFMA(t) fence vmcnt(4)+lgkmcnt(0) barrier.
// vmcnt(4): drains idx+B(t+2) (and older), leaves exactly A(t+1) x4 in flight.
__global__ __launch_bounds__(512, 2) void k_main(
    const unsigned short* __restrict__ padx,   // [50001][256] bf16
    const unsigned short* __restrict__ wt,     // [256][2304] bf16
    const void* __restrict__ nbr,              // [50000][9] int64 or int32
    const int* __restrict__ flag,
    const float* __restrict__ bias,            // [256]
    float* __restrict__ out) {                 // [50000][256] f32
  __shared__ __align__(16) unsigned char sm[RSZ];
  const int tid = threadIdx.x;
  const int wv = tid >> 6, lane = tid & 63;
  const int m0 = blockIdx.x * BM;
  const int q = lane & 15, hi = lane >> 4;
  const int wm = wv >> 2, wn = wv & 3;
  const int hi8 = hi * 8;

  // bias preload
  float bv[4];
#pragma unroll
  for (int ni = 0; ni < 4; ++ni) bv[ni] = bias[wn * 64 + ni * 16 + q];

  // per-lane face bases for the 4 A-fragments (row depends on lane&15 only)
  const bool f64 = (flag[0] != 0);
  const char* nb = (const char*)nbr;
  int fb0, fb1, fb2, fb3;
  {
    int f0 = m0 + wm * 64 + 0 * 16 + q; if (f0 > NF - 1) f0 = NF - 1;
    int f1 = m0 + wm * 64 + 1 * 16 + q; if (f1 > NF - 1) f1 = NF - 1;
    int f2 = m0 + wm * 64 + 2 * 16 + q; if (f2 > NF - 1) f2 = NF - 1;
    int f3 = m0 + wm * 64 + 3 * 16 + q; if (f3 > NF - 1) f3 = NF - 1;
    fb0 = f0 * 9; fb1 = f1 * 9; fb2 = f2 * 9; fb3 = f3 * 9;
  }
#define LDIDX(fb, gg) (f64 ? (int)*(const long long*)(nb + ((fb) + (gg)) * 8) \
                           : *(const int*)(nb + ((fb) + (gg)) * 4))

  // B staging setup (lane-linear dest tid*16; source-side slot swizzle)
  const int srcsl = ((tid & 3) ^ ((tid >> 3) & 3)) * 8;   // elems
  const unsigned short* wtb0 = wt + (tid >> 2) * KTOT + srcsl;          // rows 0..127
  const unsigned short* wtb1 = wt + (128 + (tid >> 2)) * KTOT + srcsl;  // rows 128..255

  // B fragment read offsets (bytes within one slot)
  const int slotb = (hi ^ ((q >> 1) & 3)) * 16;
  int boff[4];
#pragma unroll
  for (int ni = 0; ni < 4; ++ni) boff[ni] = (wn * 64 + ni * 16 + q) * 64 + slotb;

  f32x4 acc[4][4];
#pragma unroll
  for (int a = 0; a < 4; ++a)
#pragma unroll
    for (int b = 0; b < 4; ++b) {
      acc[a][b][0] = 0.f; acc[a][b][1] = 0.f; acc[a][b][2] = 0.f; acc[a][b][3] = 0.f;
    }

  // ---- prologue ----
  int rc0 = LDIDX(fb0, 0), rc1 = LDIDX(fb1, 0), rc2 = LDIDX(fb2, 0), rc3 = LDIDX(fb3, 0);
  int rn0 = rc0, rn1 = rc1, rn2 = rc2, rn3 = rc3;
  // stage B(0) -> slot0, B(1) -> slot1
  gll16(wtb0 + 0,  sm + 0 + tid * 16);
  gll16(wtb1 + 0,  sm + 8192 + tid * 16);
  gll16(wtb0 + 32, sm + SLOT + tid * 16);
  gll16(wtb1 + 32, sm + SLOT + 8192 + tid * 16);
  // A(0) direct (needs rc -> compiler inserts the dep wait)
  bf16x8 a0_0, a0_1, a0_2, a0_3, a1_0, a1_1, a1_2, a1_3;
  a0_0 = *(const bf16x8*)(padx + rc0 * 256 + hi8);
  a0_1 = *(const bf16x8*)(padx + rc1 * 256 + hi8);
  a0_2 = *(const bf16x8*)(padx + rc2 * 256 + hi8);
  a0_3 = *(const bf16x8*)(padx + rc3 * 256 + hi8);
  asm volatile("s_waitcnt vmcnt(4)" ::: "memory");   // B(0),B(1) resident; A(0) elastic
  __builtin_amdgcn_s_barrier();
  bf16x8 b0_0, b0_1, b0_2, b0_3, b1_0, b1_1, b1_2, b1_3;
  b0_0 = *(const bf16x8*)(sm + boff[0]);
  b0_1 = *(const bf16x8*)(sm + boff[1]);
  b0_2 = *(const bf16x8*)(sm + boff[2]);
  b0_3 = *(const bf16x8*)(sm + boff[3]);

  int oR = SLOT;        // slot of tile t+1 (frag prefetch)
  int oW = 2 * SLOT;    // slot receiving tile t+2

#define MFMA16(cA0,cA1,cA2,cA3, cB0,cB1,cB2,cB3) {                          \
    acc[0][0] = __builtin_amdgcn_mfma_f32_16x16x32_bf16(cA0, cB0, acc[0][0], 0,0,0); \
    acc[0][1] = __builtin_amdgcn_mfma_f32_16x16x32_bf16(cA0, cB1, acc[0][1], 0,0,0); \
    acc[0][2] = __builtin_amdgcn_mfma_f32_16x16x32_bf16(cA0, cB2, acc[0][2], 0,0,0); \
    acc[0][3] = __builtin_amdgcn_mfma_f32_16x16x32_bf16(cA0, cB3, acc[0][3], 0,0,0); \
    acc[1][0] = __builtin_amdgcn_mfma_f32_16x16x32_bf16(cA1, cB0, acc[1][0], 0,0,0); \
    acc[1][1] = __builtin_amdgcn_mfma_f32_16x16x32_bf16(cA1, cB1, acc[1][1], 0,0,0); \
    acc[1][2] = __builtin_amdgcn_mfma_f32_16x16x32_bf16(cA1, cB2, acc[1][2], 0,0,0); \
    acc[1][3] = __builtin_amdgcn_mfma_f32_16x16x32_bf16(cA1, cB3, acc[1][3], 0,0,0); \
    acc[2][0] = __builtin_amdgcn_mfma_f32_16x16x32_bf16(cA2, cB0, acc[2][0], 0,0,0); \
    acc[2][1] = __builtin_amdgcn_mfma_f32_16x16x32_bf16(cA2, cB1, acc[2][1], 0,0,0); \
    acc[2][2] = __builtin_amdgcn_mfma_f32_16x16x32_bf16(cA2, cB2, acc[2][2], 0,0,0); \
    acc[2][3] = __builtin_amdgcn_mfma_f32_16x16x32_bf16(cA2, cB3, acc[2][3], 0,0,0); \
    acc[3][0] = __builtin_amdgcn_mfma_f32_16x16x32_bf16(cA3, cB0, acc[3][0], 0,0,0); \
    acc[3][1] = __builtin_amdgcn_mfma_f32_16x16x32_bf16(cA3, cB1, acc[3][1], 0,0,0); \
    acc[3][2] = __builtin_amdgcn_mfma_f32_16x16x32_bf16(cA3, cB2, acc[3][2], 0,0,0); \
    acc[3][3] = __builtin_amdgcn_mfma_f32_16x16x32_bf16(cA3, cB3, acc[3][3], 0,0,0); }

  // ITER(J, curA.., curB.., nxtA.., nxtB.., ROWSET): one K32-tile.
#define ITER(J, cA0,cA1,cA2,cA3, cB0,cB1,cB2,cB3, nA0,nA1,nA2,nA3, nB0,nB1,nB2,nB3, R0,R1,R2,R3) { \
    const unsigned char* rb_ = sm + oR;                                     \
    nB0 = *(const bf16x8*)(rb_ + boff[0]);                                  \
    nB1 = *(const bf16x8*)(rb_ + boff[1]);                                  \
    nB2 = *(const bf16x8*)(rb_ + boff[2]);                                  \
    nB3 = *(const bf16x8*)(rb_ + boff[3]);                                  \
    if ((J) == 0) {                                                         \
      const int gn_ = (g >= 8) ? 8 : g + 1;                                 \
      rn0 = LDIDX(fb0, gn_); rn1 = LDIDX(fb1, gn_);                         \
      rn2 = LDIDX(fb2, gn_); rn3 = LDIDX(fb3, gn_);                         \
    }                                                                       \
    {                                                                       \
      const int kt2_ = g8 + (J) + 2;                                        \
      const int kg_ = ((kt2_ < NT) ? kt2_ : NT - 1) * 32;                   \
      gll16(wtb0 + kg_, sm + oW + tid * 16);                                \
      gll16(wtb1 + kg_, sm + oW + 8192 + tid * 16);                         \
    }                                                                       \
    __builtin_amdgcn_sched_barrier(0);                                      \
    {                                                                       \
      const int kc_ = (((J) + 1) & 7) * 32 + hi8;                           \
      nA0 = *(const bf16x8*)(padx + (R0) * 256 + kc_);                      \
      nA1 = *(const bf16x8*)(padx + (R1) * 256 + kc_);                      \
      nA2 = *(const bf16x8*)(padx + (R2) * 256 + kc_);                      \
      nA3 = *(const bf16x8*)(padx + (R3) * 256 + kc_);                      \
    }                                                                       \
    __builtin_amdgcn_sched_barrier(0);                                      \
    __builtin_amdgcn_s_setprio(1);                                          \
    MFMA16(cA0,cA1,cA2,cA3, cB0,cB1,cB2,cB3)                                \
    __builtin_amdgcn_s_setprio(0);                                          \
    __builtin_amdgcn_sched_barrier(0);                                      \
    asm volatile("s_waitcnt vmcnt(4)" ::: "memory");                        \
    asm volatile("s_waitcnt lgkmcnt(0)" ::: "memory");                      \
    __builtin_amdgcn_sched_barrier(0);                                      \
    __builtin_amdgcn_s_barrier();                                           \
    oR += SLOT; if (oR == RSZ) oR = 0;                                      \
    oW += SLOT; if (oW == RSZ) oW = 0;                                      \
  }

#pragma unroll 1
  for (int g = 0; g < 9; ++g) {
    const int g8 = g * 8;
    ITER(0, a0_0,a0_1,a0_2,a0_3, b0_0,b0_1,b0_2,b0_3, a1_0,a1_1,a1_2,a1_3, b1_0,b1_1,b1_2,b1_3, rc0,rc1,rc2,rc3)
    ITER(1, a1_0,a1_1,a1_2,a1_3, b1_0,b1_1,b1_2,b1_3, a0_0,a0_1,a0_2,a0_3, b0_0,b0_1,b0_2,b0_3, rc0,rc1,rc2,rc3)
    ITER(2, a0_0,a0_1,a0_2,a0_3, b0_0,b0_1,b0_2,b0_3, a1_0,a1_1,a1_2,a1_3, b1_0,b1_1,b1_2,b1_3, rc0,rc1,rc2,rc3)
    ITER(3, a1_0,a1_1,a1_2,a1_3, b1_0,b1_1,b1_2,b1_3, a0_0,a0_1,a0_2,a0_3, b0_0,b0_1,b0_2,b0_3, rc0,rc1,rc2,rc3)
    ITER(4, a0_0,a0_1,a0_2,a0_3, b0_0,b0_1,b0_2,b0_3, a1_0,a1_1,a1_2,a1_3, b1_0,b1_1,b1_2,b1_3, rc0,rc1,rc2,rc3)
    ITER(5, a1_0,a1_1,a1_2,a1_3, b1_0,b1_1,b1_2,b1_3, a0_0,a0_1,a0_2,a0_3, b0_0,b0_1,b0_2,b0_3, rc0,rc1,rc2,rc3)
    ITER(6, a0_0,a0_1,a0_2,a0_3, b0_0,b0_1,b0_2,b0_3, a1_0,a1_1,a1_2,a1_3, b1_0,b1_1,b1_2,b1_3, rc0,rc1,rc2,rc3)
    ITER(7, a1_0,a1_1,a1_2,a1_3, b1_0,b1_1,b1_2,b1_3, a0_0,a0_1,a0_2,a0_3, b0_0,b0_1,b0_2,b0_3, rn0,rn1,rn2,rn3)
    rc0 = rn0; rc1 = rn1; rc2 = rn2; rc3 = rn3;
  }
#undef ITER
#undef MFMA16
#undef LDIDX
  asm volatile("s_waitcnt vmcnt(0)" ::: "memory");

  // ---- epilogue: bias + store (D: col = q, row = hi*4 + r) ----
#pragma unroll
  for (int ni = 0; ni < 4; ++ni) {
    const int col = wn * 64 + ni * 16 + q;
#pragma unroll
    for (int mi = 0; mi < 4; ++mi) {
#pragma unroll
      for (int rr = 0; rr < 4; ++rr) {
        const int row = m0 + wm * 64 + mi * 16 + hi * 4 + rr;
        if (row < NF) out[row * 256 + col] = acc[mi][ni][rr] + bv[ni];
      }
    }
  }
}

extern "C" void kernel_launch(void* const* d_in, const int* in_sizes, int n_in,
                              void* d_out, int out_size, void* d_ws, size_t ws_size,
                              hipStream_t stream) {
  const float* x = (const float*)d_in[0];
  const float* wfull = (const float*)d_in[1];
  const float* bias = (const float*)d_in[2];
  const void* nbr = d_in[3];
  const unsigned char* pad = (const unsigned char*)d_in[4];
  float* out = (float*)d_out;
  char* ws = (char*)d_ws;

  unsigned short* wt   = (unsigned short*)(ws + WT_OFF);
  int* flag            = (int*)(ws + FLAG_OFF);
  int* cnt             = (int*)(ws + CNT_OFF);
  unsigned short* padx = (unsigned short*)(ws + PADX_OFF);

  k_prep<<<452, 256, 0, stream>>>(wfull, wt, pad, cnt, (const unsigned int*)nbr, flag);
  k_rankpadx<<<NCHUNK, 256, 0, stream>>>(x, pad, cnt, padx);
  k_main<<<NBLK, 512, 0, stream>>>(padx, wt, nbr, flag, bias, out);
}

// Round 9
// 186.362 us; speedup vs baseline: 1.1569x; 1.1569x over previous
//
#include <hip/hip_runtime.h>

#define NF    50000
#define PADP  50001
#define KN    9
#define KTOT  2304
#define NCHUNK 782
#define NT    72          // 2304/32 K-tiles
#define BM    128
#define NBLK  391         // ceil(50000/128)

// ---- ws layout (bytes) ----
#define WT_OFF   0u          // 256*2304*2 = 1179648
#define FLAG_OFF 1179648u
#define CNT_OFF  1179904u    // 782*4
#define PADX_OFF 1183744u    // 50001*256*2

typedef float f32x4 __attribute__((ext_vector_type(4)));
typedef __bf16 bf16x8 __attribute__((ext_vector_type(8)));

typedef const __attribute__((address_space(1))) unsigned int* gas_t;
typedef __attribute__((address_space(3))) unsigned int* las_t;

static __device__ __forceinline__ void gll16(const void* g, void* l) {
  __builtin_amdgcn_global_load_lds((gas_t)g, (las_t)l, 16, 0, 0);
}

static __device__ __forceinline__ unsigned short f2bf(float f) {
  unsigned int u = __builtin_bit_cast(unsigned int, f);
  u = u + 0x7fffu + ((u >> 16) & 1u);      // RNE
  return (unsigned short)(u >> 16);
}

// ---------- preprocessing ----------

// fused: weight demod+transpose (blocks 0..255) | pad chunk counts + flag (blocks 256..451)
__global__ void k_prep(const float* __restrict__ w, unsigned short* __restrict__ wt,
                       const unsigned char* __restrict__ pad, int* __restrict__ cnt,
                       const unsigned int* __restrict__ raw, int* __restrict__ flag) {
  if (blockIdx.x < 256) {
    int o = blockIdx.x;
    int i = threadIdx.x;
    const float* wr = w + (o * 256 + i) * 9;
    float wv[9];
    float s = 0.f;
#pragma unroll
    for (int k = 0; k < 9; ++k) { wv[k] = wr[k]; s += wv[k] * wv[k]; }
#pragma unroll
    for (int d = 32; d >= 1; d >>= 1) s += __shfl_xor(s, d);
    __shared__ float red[4];
    if ((i & 63) == 0) red[i >> 6] = s;
    __syncthreads();
    float dc = rsqrtf(red[0] + red[1] + red[2] + red[3] + 1e-8f);
#pragma unroll
    for (int k = 0; k < 9; ++k)
      wt[o * KTOT + k * 256 + i] = f2bf(wv[k] * dc);
  } else {
    int cb = blockIdx.x - 256;
    int t = cb * 256 + threadIdx.x;
    bool ip = (t < PADP) ? (pad[t] != 0) : true;
    unsigned long long m = __ballot(ip);
    int c = t >> 6;
    if ((threadIdx.x & 63) == 0 && c < NCHUNK) cnt[c] = __popcll(m);
    if (cb == 0 && threadIdx.x < 64) {
      unsigned int v = raw[threadIdx.x * 2 + 1];
      unsigned long long nz = __ballot(v != 0u);
      if (threadIdx.x == 0) flag[0] = (nz == 0ull) ? 1 : 0;
    }
  }
}

// one block per 64-row chunk: prefix over cnt -> ranks -> bf16 conversion
__global__ __launch_bounds__(256) void k_rankpadx(
    const float* __restrict__ x, const unsigned char* __restrict__ pad,
    const int* __restrict__ cnt, unsigned short* __restrict__ padx) {
  const int c = blockIdx.x;
  const int tid = threadIdx.x, w = tid >> 6, lane = tid & 63;
  int s = 0;
  for (int i = tid; i < c; i += 256) s += cnt[i];
#pragma unroll
  for (int d = 32; d >= 1; d >>= 1) s += __shfl_xor(s, d);
  __shared__ int red[4];
  __shared__ int rnk[64];
  if (lane == 0) red[w] = s;
  __syncthreads();
  const int S = red[0] + red[1] + red[2] + red[3];
  if (w == 0) {
    int p = c * 64 + lane;
    bool ip = (p < PADP) ? (pad[p] != 0) : true;
    unsigned long long m = __ballot(ip);
    int before = __popcll(m & ((1ull << lane) - 1ull));
    rnk[lane] = ip ? -1 : (p - (S + before));
  }
  __syncthreads();
  const int col = lane * 4;
#pragma unroll
  for (int i = 0; i < 16; ++i) {
    int rl = i * 4 + w;
    int pp = c * 64 + rl;
    if (pp >= PADP) continue;
    int rr = rnk[rl];
    ushort4 ov;
    if (rr < 0) { ov.x = 0; ov.y = 0; ov.z = 0; ov.w = 0; }
    else {
      const float4 v = *(const float4*)(x + rr * 256 + col);
      ov.x = f2bf(v.x); ov.y = f2bf(v.y); ov.z = f2bf(v.z); ov.w = f2bf(v.w);
    }
    *(ushort4*)(padx + pp * 256 + col) = ov;
  }
}

// ---------- main gathered GEMM ----------
// BM=128 x BN=256 x BK=32, 512 thr (8 waves 2M x 4N), wave-tile 64x64 (4x4).
// KEY CHANGE vs R1-R8: B (weights) NEVER touches LDS — loaded direct
// global(L2)->register (4 dwordx4/wave/K32, prefetched 1 K-tile ahead,
// ping-pong named sets). LDS carries only A: ring-2 x 8KB, 1 gll16/thread/K32.
// LDS traffic per K32: 32KB read + 8KB write (was 64+24) -> below MFMA time.
// One __syncthreads per K32 (72 total, same as R1); compiler-managed waits;
// 2 blocks/CU forced via launch_bounds VGPR cap (TLP covers the sync drain).
__global__ __launch_bounds__(512, 4) void k_main(
    const unsigned short* __restrict__ padx,   // [50001][256] bf16
    const unsigned short* __restrict__ wt,     // [256][2304] bf16
    const void* __restrict__ nbr,              // [50000][9] int64 or int32
    const int* __restrict__ flag,
    const float* __restrict__ bias,            // [256]
    float* __restrict__ out) {                 // [50000][256] f32
  __shared__ __align__(16) unsigned char sm[20992];   // 2x8KB A ring + idx cache
  const int tid = threadIdx.x;
  const int wv = tid >> 6, lane = tid & 63;
  const int m0 = blockIdx.x * BM;
  int* idx_lds = (int*)(sm + 16384);           // 128*9 ints

  const int q = lane & 15, hi = lane >> 4;
  const int wm = wv >> 2, wn = wv & 3;

  // bias preload
  float bv[4];
#pragma unroll
  for (int ni = 0; ni < 4; ++ni) bv[ni] = bias[wn * 64 + ni * 16 + q];

  // idx cache (reads raw int64/int32 directly)
  const bool f64 = (flag[0] != 0);
  const long long* n64 = (const long long*)nbr;
  const int* n32 = (const int*)nbr;
  for (int e = tid; e < BM * 9; e += 512) {
    int f = m0 + e / 9;
    if (f >= NF) f = NF - 1;
    int k = e - (e / 9) * 9;
    idx_lds[e] = f64 ? (int)n64[f * KN + k] : n32[f * KN + k];
  }
  __syncthreads();

  // ---- A staging setup: 1 gll16/thread/K32, lane-linear dest, src-side swizzle
  const int rA = tid >> 2;                                  // LDS row 0..127
  const int srcsl = ((tid & 3) ^ ((tid >> 3) & 3)) * 8;     // swizzled src slot (elems)
  const int aDst = tid * 16;

  // ---- A fragment read offsets (conflict-free, R1-verified) ----
  const int slotb = (hi ^ ((q >> 1) & 3)) * 16;
  int aoff[4];
#pragma unroll
  for (int mi = 0; mi < 4; ++mi) aoff[mi] = (wm * 64 + mi * 16 + q) * 64 + slotb;

  // ---- B direct-load bases (per ni): lane reads wt[col][k...k+8], 16B ----
  const unsigned short* wB0 = wt + (wn * 64 +  0 + q) * KTOT + hi * 8;
  const unsigned short* wB1 = wt + (wn * 64 + 16 + q) * KTOT + hi * 8;
  const unsigned short* wB2 = wt + (wn * 64 + 32 + q) * KTOT + hi * 8;
  const unsigned short* wB3 = wt + (wn * 64 + 48 + q) * KTOT + hi * 8;

  f32x4 acc[4][4];
#pragma unroll
  for (int a = 0; a < 4; ++a)
#pragma unroll
    for (int b = 0; b < 4; ++b) {
      acc[a][b][0] = 0.f; acc[a][b][1] = 0.f; acc[a][b][2] = 0.f; acc[a][b][3] = 0.f;
    }

  // ---- prologue: stage A(0), load B(0) ----
  {
    const int p0 = idx_lds[rA * 9];
    gll16(padx + p0 * 256 + srcsl, sm + aDst);
  }
  bf16x8 b00 = *(const bf16x8*)(wB0);
  bf16x8 b01 = *(const bf16x8*)(wB1);
  bf16x8 b02 = *(const bf16x8*)(wB2);
  bf16x8 b03 = *(const bf16x8*)(wB3);
  __syncthreads();                       // A(0) + B(0) resident
  bf16x8 b10 = b00, b11 = b01, b12 = b02, b13 = b03;

#define BITER(T, cB0,cB1,cB2,cB3, nB0,nB1,nB2,nB3) {                        \
    const int u_ = (T) + 1;                                                 \
    if (u_ < NT) {                                                          \
      const int p_ = idx_lds[rA * 9 + (u_ >> 3)];                           \
      gll16(padx + p_ * 256 + (u_ & 7) * 32 + srcsl,                        \
            sm + (u_ & 1) * 8192 + aDst);                                   \
      nB0 = *(const bf16x8*)(wB0 + u_ * 32);                                \
      nB1 = *(const bf16x8*)(wB1 + u_ * 32);                                \
      nB2 = *(const bf16x8*)(wB2 + u_ * 32);                                \
      nB3 = *(const bf16x8*)(wB3 + u_ * 32);                                \
    }                                                                       \
    __builtin_amdgcn_sched_barrier(0);                                      \
    {                                                                       \
      const unsigned char* rb_ = sm + ((T) & 1) * 8192;                     \
      _Pragma("unroll")                                                     \
      for (int mi = 0; mi < 4; ++mi) {                                      \
        bf16x8 af_ = *(const bf16x8*)(rb_ + aoff[mi]);                      \
        acc[mi][0] = __builtin_amdgcn_mfma_f32_16x16x32_bf16(af_, cB0, acc[mi][0], 0,0,0); \
        acc[mi][1] = __builtin_amdgcn_mfma_f32_16x16x32_bf16(af_, cB1, acc[mi][1], 0,0,0); \
        acc[mi][2] = __builtin_amdgcn_mfma_f32_16x16x32_bf16(af_, cB2, acc[mi][2], 0,0,0); \
        acc[mi][3] = __builtin_amdgcn_mfma_f32_16x16x32_bf16(af_, cB3, acc[mi][3], 0,0,0); \
      }                                                                     \
    }                                                                       \
    __syncthreads();                                                        \
  }

#pragma unroll 1
  for (int t2 = 0; t2 < NT; t2 += 2) {
    BITER(t2,     b00,b01,b02,b03, b10,b11,b12,b13)
    BITER(t2 + 1, b10,b11,b12,b13, b00,b01,b02,b03)
  }
#undef BITER

  // ---- epilogue: bias + store (D: col = q, row = hi*4 + r) ----
#pragma unroll
  for (int ni = 0; ni < 4; ++ni) {
    const int col = wn * 64 + ni * 16 + q;
#pragma unroll
    for (int mi = 0; mi < 4; ++mi) {
#pragma unroll
      for (int rr = 0; rr < 4; ++rr) {
        const int row = m0 + wm * 64 + mi * 16 + hi * 4 + rr;
        if (row < NF) out[row * 256 + col] = acc[mi][ni][rr] + bv[ni];
      }
    }
  }
}

extern "C" void kernel_launch(void* const* d_in, const int* in_sizes, int n_in,
                              void* d_out, int out_size, void* d_ws, size_t ws_size,
                              hipStream_t stream) {
  const float* x = (const float*)d_in[0];
  const float* wfull = (const float*)d_in[1];
  const float* bias = (const float*)d_in[2];
  const void* nbr = d_in[3];
  const unsigned char* pad = (const unsigned char*)d_in[4];
  float* out = (float*)d_out;
  char* ws = (char*)d_ws;

  unsigned short* wt   = (unsigned short*)(ws + WT_OFF);
  int* flag            = (int*)(ws + FLAG_OFF);
  int* cnt             = (int*)(ws + CNT_OFF);
  unsigned short* padx = (unsigned short*)(ws + PADX_OFF);

  k_prep<<<452, 256, 0, stream>>>(wfull, wt, pad, cnt, (const unsigned int*)nbr, flag);
  k_rankpadx<<<NCHUNK, 256, 0, stream>>>(x, pad, cnt, padx);
  k_main<<<NBLK, 512, 0, stream>>>(padx, wt, nbr, flag, bias, out);
}